// Round 8
// baseline (108.360 us; speedup 1.0000x reference)
//
#include <hip/hip_runtime.h>
#include <math.h>

#define NNODE 32768
#define NTHR  256
#define GRID_MAIN 2048

// fast guarded reciprocal (distance path only; branch boundaries are continuous)
__device__ __forceinline__ float rguard(float d) {
    float dd = (fabsf(d) < 1e-12f) ? 1e-12f : d;
    return __builtin_amdgcn_rcpf(dd);
}

// identical cell computation used by both the marking phase and the sum phase
__device__ __forceinline__ void cell_of(float px, float py, float pz,
                                        int& x0, int& y0, int& z0,
                                        float& wx, float& wy, float& wz) {
#pragma clang fp contract(off)
    float fx = (px + 1.0f) * 0.5f * 31.0f;
    float fy = (py + 1.0f) * 0.5f * 31.0f;
    float fz = (pz + 1.0f) * 0.5f * 31.0f;
    float x0f = floorf(fx), y0f = floorf(fy), z0f = floorf(fz);
    wx = fx - x0f; wy = fy - y0f; wz = fz - z0f;
    x0 = (int)fmaxf(fminf(x0f, 33.0f), -2.0f);
    y0 = (int)fmaxf(fminf(y0f, 33.0f), -2.0f);
    z0 = (int)fmaxf(fminf(z0f, 33.0f), -2.0f);
}

// block-cooperative bbox of hull 1 -> center/scale in every thread's registers.
__device__ __forceinline__ void bbox_of(const float* __restrict__ verts, int V,
                                        float& ocx, float& ocy, float& ocz,
                                        float& osc) {
#pragma clang fp contract(off)
    const float* v1 = verts + (size_t)V * 3;  // hull 1
    float mn[3] = {1e30f, 1e30f, 1e30f};
    float mx[3] = {-1e30f, -1e30f, -1e30f};
    for (int i = threadIdx.x; i < V; i += NTHR) {
        for (int c = 0; c < 3; ++c) {
            float val = v1[i * 3 + c];
            mn[c] = fminf(mn[c], val);
            mx[c] = fmaxf(mx[c], val);
        }
    }
    for (int off = 32; off >= 1; off >>= 1) {
        for (int c = 0; c < 3; ++c) {
            mn[c] = fminf(mn[c], __shfl_down(mn[c], off));
            mx[c] = fmaxf(mx[c], __shfl_down(mx[c], off));
        }
    }
    __shared__ float smn[4][3], smx[4][3];
    int wv = threadIdx.x >> 6, lane = threadIdx.x & 63;
    if (lane == 0)
        for (int c = 0; c < 3; ++c) { smn[wv][c] = mn[c]; smx[wv][c] = mx[c]; }
    __syncthreads();
    float ext = -1e30f, cc[3];
    for (int c = 0; c < 3; ++c) {
        float lo = fminf(fminf(smn[0][c], smn[1][c]), fminf(smn[2][c], smn[3][c]));
        float hi = fmaxf(fmaxf(smx[0][c], smx[1][c]), fmaxf(smx[2][c], smx[3][c]));
        cc[c] = (lo + hi) * 0.5f;
        ext = fmaxf(ext, hi - lo);
    }
    ocx = cc[0]; ocy = cc[1]; ocz = cc[2];
    osc = (1.0f + 0.2f) * 0.5f * ext;
    __syncthreads();
}

// per-(point, triangle) distance + parity contribution (math byte-identical to r7)
__device__ __forceinline__ void tri_pt(const float* __restrict__ tri, int f, int F,
                                       float px, float py, float pz,
                                       float& mind2, int& h) {
    if (f >= F) return;
    const float* r = tri + (size_t)f * 12;
    float ax = r[0], ay = r[1], az = r[2];
    float bx = r[3], by = r[4], bz = r[5];
    float cx = r[6], cy = r[7], cz = r[8];
    float inv = r[9], det = r[10];
    float abx = bx - ax, aby = by - ay, abz = bz - az;
    float acx = cx - ax, acy = cy - ay, acz = cz - az;
    float apx = px - ax, apy = py - ay, apz = pz - az;
    // distance path: contraction + fast rcp (continuous at all branch bounds)
    {
#pragma clang fp contract(fast)
        float d1 = abx * apx + aby * apy + abz * apz;
        float d2 = acx * apx + acy * apy + acz * apz;
        float bpx = px - bx, bpy = py - by, bpz = pz - bz;
        float d3 = abx * bpx + aby * bpy + abz * bpz;
        float d4 = acx * bpx + acy * bpy + acz * bpz;
        float cpx = px - cx, cpy = py - cy, cpz = pz - cz;
        float d5 = abx * cpx + aby * cpy + abz * cpz;
        float d6 = acx * cpx + acy * cpy + acz * cpz;
        float vc = d1 * d4 - d3 * d2;
        float vb = d5 * d2 - d1 * d6;
        float va = d3 * d6 - d5 * d4;
        float denom = va + vb + vc;
        float rd = rguard(denom);
        float v_in = vb * rd, w_in = vc * rd;
        float rx = ax + abx * v_in + acx * w_in;
        float ry = ay + aby * v_in + acy * w_in;
        float rz = az + abz * v_in + acz * w_in;
        if (va <= 0.0f && (d4 - d3) >= 0.0f && (d5 - d6) >= 0.0f) {
            float w2 = (d4 - d3) * rguard((d4 - d3) + (d5 - d6));
            rx = bx + (cx - bx) * w2; ry = by + (cy - by) * w2; rz = bz + (cz - bz) * w2;
        }
        if (vb <= 0.0f && d2 >= 0.0f && d6 <= 0.0f) {
            float w2 = d2 * rguard(d2 - d6);
            rx = ax + acx * w2; ry = ay + acy * w2; rz = az + acz * w2;
        }
        if (vc <= 0.0f && d1 >= 0.0f && d3 <= 0.0f) {
            float w2 = d1 * rguard(d1 - d3);
            rx = ax + abx * w2; ry = ay + aby * w2; rz = az + abz * w2;
        }
        if (d6 >= 0.0f && d5 <= d6) { rx = cx; ry = cy; rz = cz; }
        if (d3 >= 0.0f && d4 <= d3) { rx = bx; ry = by; rz = bz; }
        if (d1 <= 0.0f && d2 <= 0.0f) { rx = ax; ry = ay; rz = az; }
        float ddx = px - rx, ddy = py - ry, ddz = pz - rz;
        mind2 = fminf(mind2, ddx * ddx + ddy * ddy + ddz * ddz);
    }
    // parity path: bit-exact (a flip is a large, discontinuous loss change)
    {
#pragma clang fp contract(off)
        float u = (apy * (-acz) + apz * acy) * inv;
        float qx = apy * abz - apz * aby;
        float qy = apz * abx - apx * abz;
        float qz = apx * aby - apy * abx;
        float v = qx * inv;
        float tt = (acx * qx + acy * qy + acz * qz) * inv;
        h += (fabsf(det) > 1e-9f && u >= 0.0f && u <= 1.0f && v >= 0.0f &&
              (u + v) <= 1.0f && tt > 0.0f) ? 1 : 0;
    }
}

// ---- setup (33 blocks): block0 = LDS-bitmap mark+compact; blocks 1..32 =
//      triangle records + d2b/hits/done init. No k_init, no global flags. ----
__global__ void __launch_bounds__(NTHR) k_setup(
        const float* __restrict__ verts, const int* __restrict__ faces,
        float* __restrict__ tri, unsigned int* __restrict__ d2b,
        int* __restrict__ hits, int* __restrict__ cnt, int* __restrict__ list,
        int* __restrict__ done, int V, int F) {
    float cx0, cy0, cz0, sc;
    bbox_of(verts, V, cx0, cy0, cz0, sc);
    const int b = (int)blockIdx.x, tid = threadIdx.x;

    if (b == 0) {
        // mark active grid nodes in a 32768-bit LDS bitmap, then scan-compact.
        __shared__ unsigned bm[NNODE / 32];   // 4 KB
        __shared__ int scnt[NTHR];
        for (int k = 0; k < 4; ++k) bm[tid * 4 + k] = 0u;
        __syncthreads();
        for (int i = tid; i < V; i += NTHR) {
#pragma clang fp contract(off)
            float px = (verts[i * 3 + 0] - cx0) / sc;  // hull-0 vertex
            float py = (verts[i * 3 + 1] - cy0) / sc;
            float pz = (verts[i * 3 + 2] - cz0) / sc;
            int x0, y0, z0; float wx, wy, wz;
            cell_of(px, py, pz, x0, y0, z0, wx, wy, wz);
            for (int k = 0; k < 8; ++k) {
                int zi = z0 + ((k >> 2) & 1), yi = y0 + ((k >> 1) & 1),
                    xi = x0 + (k & 1);
                if ((unsigned)zi < 32u && (unsigned)yi < 32u && (unsigned)xi < 32u) {
                    int node = (zi * 32 + yi) * 32 + xi;
                    atomicOr(&bm[node >> 5], 1u << (node & 31));
                }
            }
        }
        __syncthreads();
        unsigned w0 = bm[tid * 4 + 0], w1 = bm[tid * 4 + 1],
                 w2 = bm[tid * 4 + 2], w3 = bm[tid * 4 + 3];
        int c = __popc(w0) + __popc(w1) + __popc(w2) + __popc(w3);
        scnt[tid] = c;
        __syncthreads();
        for (int off = 1; off < NTHR; off <<= 1) {  // Hillis-Steele inclusive scan
            int v_ = (tid >= off) ? scnt[tid - off] : 0;
            __syncthreads();
            scnt[tid] += v_;
            __syncthreads();
        }
        if (tid == NTHR - 1) cnt[0] = scnt[NTHR - 1];
        int off = scnt[tid] - c;
        unsigned wsv[4] = {w0, w1, w2, w3};
        for (int k = 0; k < 4; ++k) {
            unsigned w = wsv[k];
            int basebit = (tid * 4 + k) * 32;
            while (w) {
                int bb = __ffs(w) - 1;
                list[off++] = basebit + bb;
                w &= w - 1;
            }
        }
    } else {
        // triangle records: a(3) b(3) c(3) inv_det det pad (inv_det exact IEEE)
        int f = (b - 1) * NTHR + tid;
        if (f < F) {
#pragma clang fp contract(off)
            const float* v1 = verts + (size_t)V * 3;
            int i0 = faces[f * 3 + 0], i1 = faces[f * 3 + 1], i2 = faces[f * 3 + 2];
            float ax = (v1[i0 * 3 + 0] - cx0) / sc, ay = (v1[i0 * 3 + 1] - cy0) / sc,
                  az = (v1[i0 * 3 + 2] - cz0) / sc;
            float bx = (v1[i1 * 3 + 0] - cx0) / sc, by = (v1[i1 * 3 + 1] - cy0) / sc,
                  bz = (v1[i1 * 3 + 2] - cz0) / sc;
            float cx = (v1[i2 * 3 + 0] - cx0) / sc, cy = (v1[i2 * 3 + 1] - cy0) / sc,
                  cz = (v1[i2 * 3 + 2] - cz0) / sc;
            float aby = by - ay, abz = bz - az;
            float acy = cy - ay, acz = cz - az;
            float det = aby * (-acz) + abz * acy;
            float dd = (fabsf(det) < 1e-12f) ? 1e-12f : det;
            float inv = 1.0f / dd;  // IEEE — parity test must stay bit-exact
            float* r = tri + (size_t)f * 12;
            r[0] = ax; r[1] = ay; r[2] = az;
            r[3] = bx; r[4] = by; r[5] = bz;
            r[6] = cx; r[7] = cy; r[8] = cz;
            r[9] = inv; r[10] = det; r[11] = 0.0f;
        }
        int idx = (b - 1) * NTHR + tid;  // 8192 threads x 4 = 32768
        for (int j = 0; j < 4; ++j) {
            int t2 = idx + j * 8192;
            d2b[t2] = 0xFFFFFFFFu;
            hits[t2] = 0;
        }
        if (b == 1 && tid == 0) done[0] = 0;
    }
}

// ---- main: one wave per (active node, 128-triangle chunk); last block sums ----
__global__ void __launch_bounds__(NTHR) k_main(
        const float* __restrict__ tri, const int* __restrict__ list,
        const int* __restrict__ cnt, unsigned int* __restrict__ d2b,
        int* __restrict__ hits, int* __restrict__ done,
        const float* __restrict__ verts, float* __restrict__ out,
        int F, int nch, unsigned long long magic, int V) {
    const int lane = threadIdx.x & 63;
    const int wid = (int)blockIdx.x * 4 + (threadIdx.x >> 6);
    const int nw = (int)gridDim.x * 4;
    const int n = cnt[0];
    const int total = n * nch;
    for (int w = wid; w < total; w += nw) {
        const int q = (int)(((unsigned long long)(unsigned int)w * magic) >> 40);
        const int ck = w - q * nch;
        const int node = list[q];
        const int xi = node & 31, yi = (node >> 5) & 31, zi = node >> 10;
        float px, py, pz;
        {
#pragma clang fp contract(off)
            px = (float)((double)xi * (2.0 / 31.0) - 1.0);
            py = (float)((double)yi * (2.0 / 31.0) - 1.0);
            pz = (float)((double)zi * (2.0 / 31.0) - 1.0);
        }
        float mind2 = 1e30f;
        int h = 0;
        const int f0 = ck * 128 + lane;
        tri_pt(tri, f0, F, px, py, pz, mind2, h);
        tri_pt(tri, f0 + 64, F, px, py, pz, mind2, h);
        for (int off = 32; off >= 1; off >>= 1) {
            mind2 = fminf(mind2, __shfl_xor(mind2, off));
            h += __shfl_xor(h, off);
        }
        if (lane == 0) {
            atomicMin(d2b + node, __float_as_uint(mind2));
            atomicAdd(hits + node, h);
        }
    }

    // completion detection: the 2048th block to finish runs the sum phase.
    __shared__ int lastflag;
    __syncthreads();  // drains this block's atomics (vmcnt(0) before barrier)
    if (threadIdx.x == 0) {
        __threadfence();
        int prev = __hip_atomic_fetch_add(done, 1, __ATOMIC_ACQ_REL,
                                          __HIP_MEMORY_SCOPE_AGENT);
        lastflag = (prev == (int)gridDim.x - 1) ? 1 : 0;
    }
    __syncthreads();
    if (!lastflag) return;

    // ---- sum phase (block-uniform): trilinear sample at hull-0 vertices ----
    float cx, cy, cz, sc;
    bbox_of(verts, V, cx, cy, cz, sc);
    {
#pragma clang fp contract(off)
        __shared__ float sm[NTHR];
        const int tid = threadIdx.x;
        float val = 0.0f;
        for (int i = tid; i < V; i += NTHR) {
            float px = (verts[i * 3 + 0] - cx) / sc;
            float py = (verts[i * 3 + 1] - cy) / sc;
            float pz = (verts[i * 3 + 2] - cz) / sc;
            int x0, y0, z0; float wx, wy, wz;
            cell_of(px, py, pz, x0, y0, z0, wx, wy, wz);
            auto corner = [&](int zi, int yi, int xi, float w) -> float {
#pragma clang fp contract(off)
                bool valid = (zi >= 0) && (zi <= 31) && (yi >= 0) && (yi <= 31) &&
                             (xi >= 0) && (xi <= 31);
                int zc = min(max(zi, 0), 31);
                int yc = min(max(yi, 0), 31);
                int xc = min(max(xi, 0), 31);
                int idx = (zc * 32 + yc) * 32 + xc;
                // coherent-point reads: writers were device-scope atomics (G16)
                unsigned dbits = __hip_atomic_load(&d2b[idx], __ATOMIC_RELAXED,
                                                  __HIP_MEMORY_SCOPE_AGENT);
                int hh = __hip_atomic_load(&hits[idx], __ATOMIC_RELAXED,
                                           __HIP_MEMORY_SCOPE_AGENT);
                float vv = (hh & 1) ? sqrtf(fmaxf(__uint_as_float(dbits), 0.0f))
                                    : 0.0f;
                return valid ? vv * w : 0.0f;
            };
            val += corner(z0, y0, x0, (1.0f - wz) * (1.0f - wy) * (1.0f - wx))
                 + corner(z0, y0, x0 + 1, (1.0f - wz) * (1.0f - wy) * wx)
                 + corner(z0, y0 + 1, x0, (1.0f - wz) * wy * (1.0f - wx))
                 + corner(z0, y0 + 1, x0 + 1, (1.0f - wz) * wy * wx)
                 + corner(z0 + 1, y0, x0, wz * (1.0f - wy) * (1.0f - wx))
                 + corner(z0 + 1, y0, x0 + 1, wz * (1.0f - wy) * wx)
                 + corner(z0 + 1, y0 + 1, x0, wz * wy * (1.0f - wx))
                 + corner(z0 + 1, y0 + 1, x0 + 1, wz * wy * wx);
        }
        sm[tid] = val;
        __syncthreads();
        for (int s = NTHR / 2; s >= 1; s >>= 1) {
            if (tid < s) sm[tid] += sm[tid + s];
            __syncthreads();
        }
        if (tid == 0) out[0] = sm[0] * 0.25f;  // / H^2, H=2
    }
}

extern "C" void kernel_launch(void* const* d_in, const int* in_sizes, int n_in,
                              void* d_out, int out_size, void* d_ws, size_t ws_size,
                              hipStream_t stream) {
    const float* verts = (const float*)d_in[0];
    const int* faces = (const int*)d_in[1];
    float* out = (float*)d_out;
    float* ws = (float*)d_ws;

    int V = in_sizes[0] / 6;  // 2 hulls x 3 comps
    int F = in_sizes[1] / 3;

    float* tri = ws;                                   // 12*F floats
    unsigned int* d2b = (unsigned int*)(tri + 12 * (size_t)F);
    int* hits = (int*)(d2b + NNODE);
    int* cnt = hits + NNODE;
    int* done = cnt + 1;
    int* list = done + 1;                              // up to 8*V entries

    int nch = (F + 127) / 128;                         // 128 tris per wave-item
    unsigned long long magic =
        ((1ULL << 40) + (unsigned long long)nch - 1) / (unsigned long long)nch;

    k_setup<<<33, NTHR, 0, stream>>>(verts, faces, tri, d2b, hits, cnt, list, done,
                                     V, F);
    k_main<<<GRID_MAIN, NTHR, 0, stream>>>(tri, list, cnt, d2b, hits, done, verts,
                                           out, F, nch, magic, V);
}

// Round 9
// 58.532 us; speedup vs baseline: 1.8513x; 1.8513x over previous
//
#include <hip/hip_runtime.h>
#include <math.h>

#define NNODE 32768
#define NTHR  256
#define GRID_MAIN 2048

// fast guarded reciprocal (distance path only; branch boundaries are continuous)
__device__ __forceinline__ float rguard(float d) {
    float dd = (fabsf(d) < 1e-12f) ? 1e-12f : d;
    return __builtin_amdgcn_rcpf(dd);
}

// identical cell computation used by both the marking phase and the sum phase
__device__ __forceinline__ void cell_of(float px, float py, float pz,
                                        int& x0, int& y0, int& z0,
                                        float& wx, float& wy, float& wz) {
#pragma clang fp contract(off)
    float fx = (px + 1.0f) * 0.5f * 31.0f;
    float fy = (py + 1.0f) * 0.5f * 31.0f;
    float fz = (pz + 1.0f) * 0.5f * 31.0f;
    float x0f = floorf(fx), y0f = floorf(fy), z0f = floorf(fz);
    wx = fx - x0f; wy = fy - y0f; wz = fz - z0f;
    x0 = (int)fmaxf(fminf(x0f, 33.0f), -2.0f);
    y0 = (int)fmaxf(fminf(y0f, 33.0f), -2.0f);
    z0 = (int)fmaxf(fminf(z0f, 33.0f), -2.0f);
}

// block-cooperative bbox of hull 1 -> center/scale in every thread's registers.
__device__ __forceinline__ void bbox_of(const float* __restrict__ verts, int V,
                                        float& ocx, float& ocy, float& ocz,
                                        float& osc) {
#pragma clang fp contract(off)
    const float* v1 = verts + (size_t)V * 3;  // hull 1
    float mn[3] = {1e30f, 1e30f, 1e30f};
    float mx[3] = {-1e30f, -1e30f, -1e30f};
    for (int i = threadIdx.x; i < V; i += NTHR) {
        for (int c = 0; c < 3; ++c) {
            float val = v1[i * 3 + c];
            mn[c] = fminf(mn[c], val);
            mx[c] = fmaxf(mx[c], val);
        }
    }
    for (int off = 32; off >= 1; off >>= 1) {
        for (int c = 0; c < 3; ++c) {
            mn[c] = fminf(mn[c], __shfl_down(mn[c], off));
            mx[c] = fmaxf(mx[c], __shfl_down(mx[c], off));
        }
    }
    __shared__ float smn[4][3], smx[4][3];
    int wv = threadIdx.x >> 6, lane = threadIdx.x & 63;
    if (lane == 0)
        for (int c = 0; c < 3; ++c) { smn[wv][c] = mn[c]; smx[wv][c] = mx[c]; }
    __syncthreads();
    float ext = -1e30f, cc[3];
    for (int c = 0; c < 3; ++c) {
        float lo = fminf(fminf(smn[0][c], smn[1][c]), fminf(smn[2][c], smn[3][c]));
        float hi = fmaxf(fmaxf(smx[0][c], smx[1][c]), fmaxf(smx[2][c], smx[3][c]));
        cc[c] = (lo + hi) * 0.5f;
        ext = fmaxf(ext, hi - lo);
    }
    ocx = cc[0]; ocy = cc[1]; ocz = cc[2];
    osc = (1.0f + 0.2f) * 0.5f * ext;
    __syncthreads();
}

// per-(point, triangle) distance + parity contribution (math byte-identical to r7)
__device__ __forceinline__ void tri_pt(const float* __restrict__ tri, int f, int F,
                                       float px, float py, float pz,
                                       float& mind2, int& h) {
    if (f >= F) return;
    const float* r = tri + (size_t)f * 12;
    float ax = r[0], ay = r[1], az = r[2];
    float bx = r[3], by = r[4], bz = r[5];
    float cx = r[6], cy = r[7], cz = r[8];
    float inv = r[9], det = r[10];
    float abx = bx - ax, aby = by - ay, abz = bz - az;
    float acx = cx - ax, acy = cy - ay, acz = cz - az;
    float apx = px - ax, apy = py - ay, apz = pz - az;
    // distance path: contraction + fast rcp (continuous at all branch bounds)
    {
#pragma clang fp contract(fast)
        float d1 = abx * apx + aby * apy + abz * apz;
        float d2 = acx * apx + acy * apy + acz * apz;
        float bpx = px - bx, bpy = py - by, bpz = pz - bz;
        float d3 = abx * bpx + aby * bpy + abz * bpz;
        float d4 = acx * bpx + acy * bpy + acz * bpz;
        float cpx = px - cx, cpy = py - cy, cpz = pz - cz;
        float d5 = abx * cpx + aby * cpy + abz * cpz;
        float d6 = acx * cpx + acy * cpy + acz * cpz;
        float vc = d1 * d4 - d3 * d2;
        float vb = d5 * d2 - d1 * d6;
        float va = d3 * d6 - d5 * d4;
        float denom = va + vb + vc;
        float rd = rguard(denom);
        float v_in = vb * rd, w_in = vc * rd;
        float rx = ax + abx * v_in + acx * w_in;
        float ry = ay + aby * v_in + acy * w_in;
        float rz = az + abz * v_in + acz * w_in;
        if (va <= 0.0f && (d4 - d3) >= 0.0f && (d5 - d6) >= 0.0f) {
            float w2 = (d4 - d3) * rguard((d4 - d3) + (d5 - d6));
            rx = bx + (cx - bx) * w2; ry = by + (cy - by) * w2; rz = bz + (cz - bz) * w2;
        }
        if (vb <= 0.0f && d2 >= 0.0f && d6 <= 0.0f) {
            float w2 = d2 * rguard(d2 - d6);
            rx = ax + acx * w2; ry = ay + acy * w2; rz = az + acz * w2;
        }
        if (vc <= 0.0f && d1 >= 0.0f && d3 <= 0.0f) {
            float w2 = d1 * rguard(d1 - d3);
            rx = ax + abx * w2; ry = ay + aby * w2; rz = az + abz * w2;
        }
        if (d6 >= 0.0f && d5 <= d6) { rx = cx; ry = cy; rz = cz; }
        if (d3 >= 0.0f && d4 <= d3) { rx = bx; ry = by; rz = bz; }
        if (d1 <= 0.0f && d2 <= 0.0f) { rx = ax; ry = ay; rz = az; }
        float ddx = px - rx, ddy = py - ry, ddz = pz - rz;
        mind2 = fminf(mind2, ddx * ddx + ddy * ddy + ddz * ddz);
    }
    // parity path: bit-exact (a flip is a large, discontinuous loss change)
    {
#pragma clang fp contract(off)
        float u = (apy * (-acz) + apz * acy) * inv;
        float qx = apy * abz - apz * aby;
        float qy = apz * abx - apx * abz;
        float qz = apx * aby - apy * abx;
        float v = qx * inv;
        float tt = (acx * qx + acy * qy + acz * qz) * inv;
        h += (fabsf(det) > 1e-9f && u >= 0.0f && u <= 1.0f && v >= 0.0f &&
              (u + v) <= 1.0f && tt > 0.0f) ? 1 : 0;
    }
}

// ---- setup (33 blocks): block0 = LDS-bitmap mark+compact; blocks 1..32 =
//      triangle records + d2b/hits init. No k_init, no global flags. ----
__global__ void __launch_bounds__(NTHR) k_setup(
        const float* __restrict__ verts, const int* __restrict__ faces,
        float* __restrict__ tri, unsigned int* __restrict__ d2b,
        int* __restrict__ hits, int* __restrict__ cnt, int* __restrict__ list,
        int V, int F) {
    float cx0, cy0, cz0, sc;
    bbox_of(verts, V, cx0, cy0, cz0, sc);
    const int b = (int)blockIdx.x, tid = threadIdx.x;

    if (b == 0) {
        // mark active grid nodes in a 32768-bit LDS bitmap, then scan-compact.
        __shared__ unsigned bm[NNODE / 32];   // 4 KB
        __shared__ int scnt[NTHR];
        for (int k = 0; k < 4; ++k) bm[tid * 4 + k] = 0u;
        __syncthreads();
        for (int i = tid; i < V; i += NTHR) {
#pragma clang fp contract(off)
            float px = (verts[i * 3 + 0] - cx0) / sc;  // hull-0 vertex
            float py = (verts[i * 3 + 1] - cy0) / sc;
            float pz = (verts[i * 3 + 2] - cz0) / sc;
            int x0, y0, z0; float wx, wy, wz;
            cell_of(px, py, pz, x0, y0, z0, wx, wy, wz);
            for (int k = 0; k < 8; ++k) {
                int zi = z0 + ((k >> 2) & 1), yi = y0 + ((k >> 1) & 1),
                    xi = x0 + (k & 1);
                if ((unsigned)zi < 32u && (unsigned)yi < 32u && (unsigned)xi < 32u) {
                    int node = (zi * 32 + yi) * 32 + xi;
                    atomicOr(&bm[node >> 5], 1u << (node & 31));
                }
            }
        }
        __syncthreads();
        unsigned w0 = bm[tid * 4 + 0], w1 = bm[tid * 4 + 1],
                 w2 = bm[tid * 4 + 2], w3 = bm[tid * 4 + 3];
        int c = __popc(w0) + __popc(w1) + __popc(w2) + __popc(w3);
        scnt[tid] = c;
        __syncthreads();
        for (int off = 1; off < NTHR; off <<= 1) {  // Hillis-Steele inclusive scan
            int v_ = (tid >= off) ? scnt[tid - off] : 0;
            __syncthreads();
            scnt[tid] += v_;
            __syncthreads();
        }
        if (tid == NTHR - 1) cnt[0] = scnt[NTHR - 1];
        int off = scnt[tid] - c;
        unsigned wsv[4] = {w0, w1, w2, w3};
        for (int k = 0; k < 4; ++k) {
            unsigned w = wsv[k];
            int basebit = (tid * 4 + k) * 32;
            while (w) {
                int bb = __ffs(w) - 1;
                list[off++] = basebit + bb;
                w &= w - 1;
            }
        }
    } else {
        // triangle records: a(3) b(3) c(3) inv_det det pad (inv_det exact IEEE)
        int f = (b - 1) * NTHR + tid;
        if (f < F) {
#pragma clang fp contract(off)
            const float* v1 = verts + (size_t)V * 3;
            int i0 = faces[f * 3 + 0], i1 = faces[f * 3 + 1], i2 = faces[f * 3 + 2];
            float ax = (v1[i0 * 3 + 0] - cx0) / sc, ay = (v1[i0 * 3 + 1] - cy0) / sc,
                  az = (v1[i0 * 3 + 2] - cz0) / sc;
            float bx = (v1[i1 * 3 + 0] - cx0) / sc, by = (v1[i1 * 3 + 1] - cy0) / sc,
                  bz = (v1[i1 * 3 + 2] - cz0) / sc;
            float cx = (v1[i2 * 3 + 0] - cx0) / sc, cy = (v1[i2 * 3 + 1] - cy0) / sc,
                  cz = (v1[i2 * 3 + 2] - cz0) / sc;
            float aby = by - ay, abz = bz - az;
            float acy = cy - ay, acz = cz - az;
            float det = aby * (-acz) + abz * acy;
            float dd = (fabsf(det) < 1e-12f) ? 1e-12f : det;
            float inv = 1.0f / dd;  // IEEE — parity test must stay bit-exact
            float* r = tri + (size_t)f * 12;
            r[0] = ax; r[1] = ay; r[2] = az;
            r[3] = bx; r[4] = by; r[5] = bz;
            r[6] = cx; r[7] = cy; r[8] = cz;
            r[9] = inv; r[10] = det; r[11] = 0.0f;
        }
        int idx = (b - 1) * NTHR + tid;  // 8192 threads x 4 = 32768
        for (int j = 0; j < 4; ++j) {
            int t2 = idx + j * 8192;
            d2b[t2] = 0xFFFFFFFFu;
            hits[t2] = 0;
        }
    }
}

// ---- main: one wave per (active node, 128-triangle chunk), persistent grid.
//      NO device-scope fences here — they invalidate per-XCD L2 and make the
//      74 KB tri array uncacheable (round-8 lesson: FETCH 415 MB, 3x slower). ----
__global__ void __launch_bounds__(NTHR) k_main(
        const float* __restrict__ tri, const int* __restrict__ list,
        const int* __restrict__ cnt, unsigned int* __restrict__ d2b,
        int* __restrict__ hits, int F, int nch, unsigned long long magic) {
    const int lane = threadIdx.x & 63;
    const int wid = (int)blockIdx.x * 4 + (threadIdx.x >> 6);
    const int nw = (int)gridDim.x * 4;
    const int n = cnt[0];
    const int total = n * nch;
    for (int w = wid; w < total; w += nw) {
        const int q = (int)(((unsigned long long)(unsigned int)w * magic) >> 40);
        const int ck = w - q * nch;
        const int node = list[q];
        const int xi = node & 31, yi = (node >> 5) & 31, zi = node >> 10;
        float px, py, pz;
        {
#pragma clang fp contract(off)
            px = (float)((double)xi * (2.0 / 31.0) - 1.0);
            py = (float)((double)yi * (2.0 / 31.0) - 1.0);
            pz = (float)((double)zi * (2.0 / 31.0) - 1.0);
        }
        float mind2 = 1e30f;
        int h = 0;
        const int f0 = ck * 128 + lane;
        tri_pt(tri, f0, F, px, py, pz, mind2, h);
        tri_pt(tri, f0 + 64, F, px, py, pz, mind2, h);
        for (int off = 32; off >= 1; off >>= 1) {
            mind2 = fminf(mind2, __shfl_xor(mind2, off));
            h += __shfl_xor(h, off);
        }
        if (lane == 0) {
            atomicMin(d2b + node, __float_as_uint(mind2));
            atomicAdd(hits + node, h);
        }
    }
}

// ---- trilinear sample at hull-0 vertices + reduce (one 256-thread block) ----
__global__ void k_sum(const float* __restrict__ verts,
                      const unsigned int* __restrict__ d2b, const int* __restrict__ hits,
                      float* __restrict__ out, int V) {
    float cx, cy, cz, sc;
    bbox_of(verts, V, cx, cy, cz, sc);
    {
#pragma clang fp contract(off)
        __shared__ float sm[NTHR];
        const int tid = threadIdx.x;
        float val = 0.0f;
        for (int i = tid; i < V; i += NTHR) {
            float px = (verts[i * 3 + 0] - cx) / sc;
            float py = (verts[i * 3 + 1] - cy) / sc;
            float pz = (verts[i * 3 + 2] - cz) / sc;
            int x0, y0, z0; float wx, wy, wz;
            cell_of(px, py, pz, x0, y0, z0, wx, wy, wz);
            auto corner = [&](int zi, int yi, int xi, float w) -> float {
#pragma clang fp contract(off)
                bool valid = (zi >= 0) && (zi <= 31) && (yi >= 0) && (yi <= 31) &&
                             (xi >= 0) && (xi <= 31);
                int zc = min(max(zi, 0), 31);
                int yc = min(max(yi, 0), 31);
                int xc = min(max(xi, 0), 31);
                int idx = (zc * 32 + yc) * 32 + xc;
                float vv = (hits[idx] & 1)
                               ? sqrtf(fmaxf(__uint_as_float(d2b[idx]), 0.0f))
                               : 0.0f;
                return valid ? vv * w : 0.0f;
            };
            val += corner(z0, y0, x0, (1.0f - wz) * (1.0f - wy) * (1.0f - wx))
                 + corner(z0, y0, x0 + 1, (1.0f - wz) * (1.0f - wy) * wx)
                 + corner(z0, y0 + 1, x0, (1.0f - wz) * wy * (1.0f - wx))
                 + corner(z0, y0 + 1, x0 + 1, (1.0f - wz) * wy * wx)
                 + corner(z0 + 1, y0, x0, wz * (1.0f - wy) * (1.0f - wx))
                 + corner(z0 + 1, y0, x0 + 1, wz * (1.0f - wy) * wx)
                 + corner(z0 + 1, y0 + 1, x0, wz * wy * (1.0f - wx))
                 + corner(z0 + 1, y0 + 1, x0 + 1, wz * wy * wx);
        }
        sm[tid] = val;
        __syncthreads();
        for (int s = NTHR / 2; s >= 1; s >>= 1) {
            if (tid < s) sm[tid] += sm[tid + s];
            __syncthreads();
        }
        if (tid == 0) out[0] = sm[0] * 0.25f;  // / H^2, H=2
    }
}

extern "C" void kernel_launch(void* const* d_in, const int* in_sizes, int n_in,
                              void* d_out, int out_size, void* d_ws, size_t ws_size,
                              hipStream_t stream) {
    const float* verts = (const float*)d_in[0];
    const int* faces = (const int*)d_in[1];
    float* out = (float*)d_out;
    float* ws = (float*)d_ws;

    int V = in_sizes[0] / 6;  // 2 hulls x 3 comps
    int F = in_sizes[1] / 3;

    float* tri = ws;                                   // 12*F floats
    unsigned int* d2b = (unsigned int*)(tri + 12 * (size_t)F);
    int* hits = (int*)(d2b + NNODE);
    int* cnt = hits + NNODE;
    int* list = cnt + 1;                               // up to 8*V entries

    int nch = (F + 127) / 128;                         // 128 tris per wave-item
    unsigned long long magic =
        ((1ULL << 40) + (unsigned long long)nch - 1) / (unsigned long long)nch;

    k_setup<<<33, NTHR, 0, stream>>>(verts, faces, tri, d2b, hits, cnt, list, V, F);
    k_main<<<GRID_MAIN, NTHR, 0, stream>>>(tri, list, cnt, d2b, hits, F, nch, magic);
    k_sum<<<1, NTHR, 0, stream>>>(verts, d2b, hits, out, V);
}

// Round 10
// 57.516 us; speedup vs baseline: 1.8840x; 1.0177x over previous
//
#include <hip/hip_runtime.h>
#include <math.h>

#define NNODE 32768
#define NTHR  256
#define TILE  256
#define NBM   1024   // k_main blocks; 4096 waves; n <= 8*V = 6224 < 8192 -> 2 slots

// fast guarded reciprocal (distance path only; branch boundaries are continuous)
__device__ __forceinline__ float rguard(float d) {
    float dd = (fabsf(d) < 1e-12f) ? 1e-12f : d;
    return __builtin_amdgcn_rcpf(dd);
}

// identical cell computation used by both the marking phase and the sum phase
__device__ __forceinline__ void cell_of(float px, float py, float pz,
                                        int& x0, int& y0, int& z0,
                                        float& wx, float& wy, float& wz) {
#pragma clang fp contract(off)
    float fx = (px + 1.0f) * 0.5f * 31.0f;
    float fy = (py + 1.0f) * 0.5f * 31.0f;
    float fz = (pz + 1.0f) * 0.5f * 31.0f;
    float x0f = floorf(fx), y0f = floorf(fy), z0f = floorf(fz);
    wx = fx - x0f; wy = fy - y0f; wz = fz - z0f;
    x0 = (int)fmaxf(fminf(x0f, 33.0f), -2.0f);
    y0 = (int)fmaxf(fminf(y0f, 33.0f), -2.0f);
    z0 = (int)fmaxf(fminf(z0f, 33.0f), -2.0f);
}

// block-cooperative bbox of hull 1 -> center/scale in every thread's registers.
__device__ __forceinline__ void bbox_of(const float* __restrict__ verts, int V,
                                        float& ocx, float& ocy, float& ocz,
                                        float& osc) {
#pragma clang fp contract(off)
    const float* v1 = verts + (size_t)V * 3;  // hull 1
    float mn[3] = {1e30f, 1e30f, 1e30f};
    float mx[3] = {-1e30f, -1e30f, -1e30f};
    for (int i = threadIdx.x; i < V; i += NTHR) {
        for (int c = 0; c < 3; ++c) {
            float val = v1[i * 3 + c];
            mn[c] = fminf(mn[c], val);
            mx[c] = fmaxf(mx[c], val);
        }
    }
    for (int off = 32; off >= 1; off >>= 1) {
        for (int c = 0; c < 3; ++c) {
            mn[c] = fminf(mn[c], __shfl_down(mn[c], off));
            mx[c] = fmaxf(mx[c], __shfl_down(mx[c], off));
        }
    }
    __shared__ float smn[4][3], smx[4][3];
    int wv = threadIdx.x >> 6, lane = threadIdx.x & 63;
    if (lane == 0)
        for (int c = 0; c < 3; ++c) { smn[wv][c] = mn[c]; smx[wv][c] = mx[c]; }
    __syncthreads();
    float ext = -1e30f, cc[3];
    for (int c = 0; c < 3; ++c) {
        float lo = fminf(fminf(smn[0][c], smn[1][c]), fminf(smn[2][c], smn[3][c]));
        float hi = fmaxf(fmaxf(smx[0][c], smx[1][c]), fmaxf(smx[2][c], smx[3][c]));
        cc[c] = (lo + hi) * 0.5f;
        ext = fmaxf(ext, hi - lo);
    }
    ocx = cc[0]; ocy = cc[1]; ocz = cc[2];
    osc = (1.0f + 0.2f) * 0.5f * ext;
    __syncthreads();
}

// per-(node, triangle) update from a 16-float record. Distance path uses
// precomputed dots (continuous rewrites only); parity path is bit-exact
// (ab, ac, ap, inv, det identical to the reference formulation).
__device__ __forceinline__ void tri_node(
        float ax, float ay, float az, float abx, float aby, float abz,
        float acx, float acy, float acz, float inv, float det,
        float dbb, float dbc, float dcc,
        float px, float py, float pz, float& mind2, int& h) {
    float apx = px - ax, apy = py - ay, apz = pz - az;
    {
#pragma clang fp contract(fast)
        float d1 = abx * apx + aby * apy + abz * apz;
        float d2 = acx * apx + acy * apy + acz * apz;
        float d3 = d1 - dbb;   // ab.(p-b) = d1 - |ab|^2
        float d4 = d2 - dbc;   // ac.(p-b) = d2 - ab.ac
        float d5 = d1 - dbc;   // ab.(p-c) = d1 - ab.ac
        float d6 = d2 - dcc;   // ac.(p-c) = d2 - |ac|^2
        float vc = d1 * d4 - d3 * d2;
        float vb = d5 * d2 - d1 * d6;
        float va = d3 * d6 - d5 * d4;
        float denom = va + vb + vc;
        float rd = rguard(denom);
        float v_in = vb * rd, w_in = vc * rd;
        float rx = ax + abx * v_in + acx * w_in;
        float ry = ay + aby * v_in + acy * w_in;
        float rz = az + abz * v_in + acz * w_in;
        if (va <= 0.0f && (d4 - d3) >= 0.0f && (d5 - d6) >= 0.0f) {
            float w2 = (d4 - d3) * rguard((d4 - d3) + (d5 - d6));
            rx = ax + abx + (acx - abx) * w2;   // b + (c-b)*w
            ry = ay + aby + (acy - aby) * w2;
            rz = az + abz + (acz - abz) * w2;
        }
        if (vb <= 0.0f && d2 >= 0.0f && d6 <= 0.0f) {
            float w2 = d2 * rguard(d2 - d6);
            rx = ax + acx * w2; ry = ay + acy * w2; rz = az + acz * w2;
        }
        if (vc <= 0.0f && d1 >= 0.0f && d3 <= 0.0f) {
            float w2 = d1 * rguard(d1 - d3);
            rx = ax + abx * w2; ry = ay + aby * w2; rz = az + abz * w2;
        }
        if (d6 >= 0.0f && d5 <= d6) { rx = ax + acx; ry = ay + acy; rz = az + acz; }
        if (d3 >= 0.0f && d4 <= d3) { rx = ax + abx; ry = ay + aby; rz = az + abz; }
        if (d1 <= 0.0f && d2 <= 0.0f) { rx = ax; ry = ay; rz = az; }
        float ddx = px - rx, ddy = py - ry, ddz = pz - rz;
        mind2 = fminf(mind2, ddx * ddx + ddy * ddy + ddz * ddz);
    }
    {
#pragma clang fp contract(off)
        float u = (apy * (-acz) + apz * acy) * inv;
        float qx = apy * abz - apz * aby;
        float qy = apz * abx - apx * abz;
        float qz = apx * aby - apy * abx;
        float v = qx * inv;
        float tt = (acx * qx + acy * qy + acz * qz) * inv;
        h += (fabsf(det) > 1e-9f && u >= 0.0f && u <= 1.0f && v >= 0.0f &&
              (u + v) <= 1.0f && tt > 0.0f) ? 1 : 0;
    }
}

// ---- setup: block0 = LDS-bitmap mark+compact active nodes; blocks >=1 =
//      16-float triangle records. No d2b/hits init needed (k_sum only reads
//      marked nodes; k_main writes every marked node with plain stores). ----
__global__ void __launch_bounds__(NTHR) k_setup(
        const float* __restrict__ verts, const int* __restrict__ faces,
        float* __restrict__ tri, int* __restrict__ cnt, int* __restrict__ list,
        int V, int F) {
    float cx0, cy0, cz0, sc;
    bbox_of(verts, V, cx0, cy0, cz0, sc);
    const int b = (int)blockIdx.x, tid = threadIdx.x;

    if (b == 0) {
        __shared__ unsigned bm[NNODE / 32];   // 4 KB bitmap
        __shared__ int scnt[NTHR];
        for (int k = 0; k < 4; ++k) bm[tid * 4 + k] = 0u;
        __syncthreads();
        for (int i = tid; i < V; i += NTHR) {
#pragma clang fp contract(off)
            float px = (verts[i * 3 + 0] - cx0) / sc;  // hull-0 vertex
            float py = (verts[i * 3 + 1] - cy0) / sc;
            float pz = (verts[i * 3 + 2] - cz0) / sc;
            int x0, y0, z0; float wx, wy, wz;
            cell_of(px, py, pz, x0, y0, z0, wx, wy, wz);
            for (int k = 0; k < 8; ++k) {
                int zi = z0 + ((k >> 2) & 1), yi = y0 + ((k >> 1) & 1),
                    xi = x0 + (k & 1);
                if ((unsigned)zi < 32u && (unsigned)yi < 32u && (unsigned)xi < 32u) {
                    int node = (zi * 32 + yi) * 32 + xi;
                    atomicOr(&bm[node >> 5], 1u << (node & 31));
                }
            }
        }
        __syncthreads();
        unsigned w0 = bm[tid * 4 + 0], w1 = bm[tid * 4 + 1],
                 w2 = bm[tid * 4 + 2], w3 = bm[tid * 4 + 3];
        int c = __popc(w0) + __popc(w1) + __popc(w2) + __popc(w3);
        scnt[tid] = c;
        __syncthreads();
        for (int off = 1; off < NTHR; off <<= 1) {  // Hillis-Steele inclusive scan
            int v_ = (tid >= off) ? scnt[tid - off] : 0;
            __syncthreads();
            scnt[tid] += v_;
            __syncthreads();
        }
        if (tid == NTHR - 1) cnt[0] = scnt[NTHR - 1];
        int off = scnt[tid] - c;
        unsigned wsv[4] = {w0, w1, w2, w3};
        for (int k = 0; k < 4; ++k) {
            unsigned w = wsv[k];
            int basebit = (tid * 4 + k) * 32;
            while (w) {
                int bb = __ffs(w) - 1;
                list[off++] = basebit + bb;
                w &= w - 1;
            }
        }
    } else {
        // record: a(3) ab(3) ac(3) inv det |ab|^2 ab.ac |ac|^2 pad pad
        int f = (b - 1) * NTHR + tid;
        if (f < F) {
#pragma clang fp contract(off)
            const float* v1 = verts + (size_t)V * 3;
            int i0 = faces[f * 3 + 0], i1 = faces[f * 3 + 1], i2 = faces[f * 3 + 2];
            float ax = (v1[i0 * 3 + 0] - cx0) / sc, ay = (v1[i0 * 3 + 1] - cy0) / sc,
                  az = (v1[i0 * 3 + 2] - cz0) / sc;
            float bx = (v1[i1 * 3 + 0] - cx0) / sc, by = (v1[i1 * 3 + 1] - cy0) / sc,
                  bz = (v1[i1 * 3 + 2] - cz0) / sc;
            float cx = (v1[i2 * 3 + 0] - cx0) / sc, cy = (v1[i2 * 3 + 1] - cy0) / sc,
                  cz = (v1[i2 * 3 + 2] - cz0) / sc;
            float abx = bx - ax, aby = by - ay, abz = bz - az;
            float acx = cx - ax, acy = cy - ay, acz = cz - az;
            float det = aby * (-acz) + abz * acy;
            float dd = (fabsf(det) < 1e-12f) ? 1e-12f : det;
            float inv = 1.0f / dd;  // IEEE — parity test must stay bit-exact
            float* r = tri + (size_t)f * 16;
            r[0] = ax;  r[1] = ay;  r[2] = az;
            r[3] = abx; r[4] = aby; r[5] = abz;
            r[6] = acx; r[7] = acy; r[8] = acz;
            r[9] = inv; r[10] = det;
            r[11] = abx * abx + aby * aby + abz * abz;   // |ab|^2
            r[12] = abx * acx + aby * acy + abz * acz;   // ab.ac
            r[13] = acx * acx + acy * acy + acz * acz;   // |ac|^2
            r[14] = 0.0f; r[15] = 0.0f;
        }
    }
}

// ---- main: wave-per-node (up to 2 slots), block-tiled LDS SoA staging.
//      No atomics, no global flags, conflict-free LDS (bank = index mod 32). ----
__global__ void __launch_bounds__(NTHR) k_main(
        const float* __restrict__ tri, const int* __restrict__ list,
        const int* __restrict__ cnt, unsigned int* __restrict__ d2b,
        int* __restrict__ hits, int F) {
    const int n = cnt[0];
    if ((int)blockIdx.x * 4 >= n) return;   // whole block idle (uniform)
    __shared__ float s[16][TILE];
    const int tid = threadIdx.x;
    const int lane = tid & 63;
    const int wgid = (int)blockIdx.x * 4 + (tid >> 6);   // 0..4095

    int nd0 = (wgid < n) ? list[wgid] : -1;
    int nd1 = (wgid + 4096 < n) ? list[wgid + 4096] : -1;
    float p0x = 0, p0y = 0, p0z = 0, p1x = 0, p1y = 0, p1z = 0;
    {
#pragma clang fp contract(off)
        if (nd0 >= 0) {
            p0x = (float)((double)(nd0 & 31) * (2.0 / 31.0) - 1.0);
            p0y = (float)((double)((nd0 >> 5) & 31) * (2.0 / 31.0) - 1.0);
            p0z = (float)((double)(nd0 >> 10) * (2.0 / 31.0) - 1.0);
        }
        if (nd1 >= 0) {
            p1x = (float)((double)(nd1 & 31) * (2.0 / 31.0) - 1.0);
            p1y = (float)((double)((nd1 >> 5) & 31) * (2.0 / 31.0) - 1.0);
            p1z = (float)((double)(nd1 >> 10) * (2.0 / 31.0) - 1.0);
        }
    }
    float m0 = 1e30f, m1 = 1e30f;
    int h0 = 0, h1 = 0;

    const int ntile = (F + TILE - 1) / TILE;
    for (int t = 0; t < ntile; ++t) {
        const int base = t * TILE;
        {   // stage one tri per thread: 4x dwordx4 global, 16x conflict-free b32 LDS
            int f = base + tid;
            if (f < F) {
                const float4* g = (const float4*)(tri + (size_t)f * 16);
                float4 r0 = g[0], r1 = g[1], r2 = g[2], r3 = g[3];
                s[0][tid] = r0.x;  s[1][tid] = r0.y;  s[2][tid] = r0.z;  s[3][tid] = r0.w;
                s[4][tid] = r1.x;  s[5][tid] = r1.y;  s[6][tid] = r1.z;  s[7][tid] = r1.w;
                s[8][tid] = r2.x;  s[9][tid] = r2.y;  s[10][tid] = r2.z; s[11][tid] = r2.w;
                s[12][tid] = r3.x; s[13][tid] = r3.y; s[14][tid] = r3.z; s[15][tid] = r3.w;
            }
        }
        __syncthreads();
        const int tn = min(TILE, F - base);
        for (int mi = 0; mi < TILE / 64; ++mi) {
            int j = lane + (mi << 6);
            if (j < tn) {
                float ax = s[0][j], ay = s[1][j], az = s[2][j];
                float abx = s[3][j], aby = s[4][j], abz = s[5][j];
                float acx = s[6][j], acy = s[7][j], acz = s[8][j];
                float inv = s[9][j], det = s[10][j];
                float dbb = s[11][j], dbc = s[12][j], dcc = s[13][j];
                if (nd0 >= 0)
                    tri_node(ax, ay, az, abx, aby, abz, acx, acy, acz, inv, det,
                             dbb, dbc, dcc, p0x, p0y, p0z, m0, h0);
                if (nd1 >= 0)
                    tri_node(ax, ay, az, abx, aby, abz, acx, acy, acz, inv, det,
                             dbb, dbc, dcc, p1x, p1y, p1z, m1, h1);
            }
        }
        __syncthreads();
    }
    for (int off = 32; off >= 1; off >>= 1) {
        m0 = fminf(m0, __shfl_xor(m0, off)); h0 += __shfl_xor(h0, off);
        m1 = fminf(m1, __shfl_xor(m1, off)); h1 += __shfl_xor(h1, off);
    }
    if (lane == 0) {
        if (nd0 >= 0) { d2b[nd0] = __float_as_uint(m0); hits[nd0] = h0; }
        if (nd1 >= 0) { d2b[nd1] = __float_as_uint(m1); hits[nd1] = h1; }
    }
}

// ---- trilinear sample at hull-0 vertices + reduce (one 256-thread block) ----
__global__ void k_sum(const float* __restrict__ verts,
                      const unsigned int* __restrict__ d2b, const int* __restrict__ hits,
                      float* __restrict__ out, int V) {
    float cx, cy, cz, sc;
    bbox_of(verts, V, cx, cy, cz, sc);
    {
#pragma clang fp contract(off)
        __shared__ float sm[NTHR];
        const int tid = threadIdx.x;
        float val = 0.0f;
        for (int i = tid; i < V; i += NTHR) {
            float px = (verts[i * 3 + 0] - cx) / sc;
            float py = (verts[i * 3 + 1] - cy) / sc;
            float pz = (verts[i * 3 + 2] - cz) / sc;
            int x0, y0, z0; float wx, wy, wz;
            cell_of(px, py, pz, x0, y0, z0, wx, wy, wz);
            auto corner = [&](int zi, int yi, int xi, float w) -> float {
#pragma clang fp contract(off)
                bool valid = (zi >= 0) && (zi <= 31) && (yi >= 0) && (yi <= 31) &&
                             (xi >= 0) && (xi <= 31);
                int zc = min(max(zi, 0), 31);
                int yc = min(max(yi, 0), 31);
                int xc = min(max(xi, 0), 31);
                int idx = (zc * 32 + yc) * 32 + xc;
                float vv = (hits[idx] & 1)
                               ? sqrtf(fmaxf(__uint_as_float(d2b[idx]), 0.0f))
                               : 0.0f;
                return valid ? vv * w : 0.0f;
            };
            val += corner(z0, y0, x0, (1.0f - wz) * (1.0f - wy) * (1.0f - wx))
                 + corner(z0, y0, x0 + 1, (1.0f - wz) * (1.0f - wy) * wx)
                 + corner(z0, y0 + 1, x0, (1.0f - wz) * wy * (1.0f - wx))
                 + corner(z0, y0 + 1, x0 + 1, (1.0f - wz) * wy * wx)
                 + corner(z0 + 1, y0, x0, wz * (1.0f - wy) * (1.0f - wx))
                 + corner(z0 + 1, y0, x0 + 1, wz * (1.0f - wy) * wx)
                 + corner(z0 + 1, y0 + 1, x0, wz * wy * (1.0f - wx))
                 + corner(z0 + 1, y0 + 1, x0 + 1, wz * wy * wx);
        }
        sm[tid] = val;
        __syncthreads();
        for (int ss = NTHR / 2; ss >= 1; ss >>= 1) {
            if (tid < ss) sm[tid] += sm[tid + ss];
            __syncthreads();
        }
        if (tid == 0) out[0] = sm[0] * 0.25f;  // / H^2, H=2
    }
}

extern "C" void kernel_launch(void* const* d_in, const int* in_sizes, int n_in,
                              void* d_out, int out_size, void* d_ws, size_t ws_size,
                              hipStream_t stream) {
    const float* verts = (const float*)d_in[0];
    const int* faces = (const int*)d_in[1];
    float* out = (float*)d_out;
    float* ws = (float*)d_ws;

    int V = in_sizes[0] / 6;  // 2 hulls x 3 comps
    int F = in_sizes[1] / 3;

    float* tri = ws;                                   // 16*F floats (64B records)
    unsigned int* d2b = (unsigned int*)(tri + 16 * (size_t)F);
    int* hits = (int*)(d2b + NNODE);
    int* cnt = hits + NNODE;
    int* list = cnt + 1;                               // up to 8*V entries

    int nrec = (F + NTHR - 1) / NTHR;
    k_setup<<<1 + nrec, NTHR, 0, stream>>>(verts, faces, tri, cnt, list, V, F);
    k_main<<<NBM, NTHR, 0, stream>>>(tri, list, cnt, d2b, hits, F);
    k_sum<<<1, NTHR, 0, stream>>>(verts, d2b, hits, out, V);
}

// Round 11
// 47.545 us; speedup vs baseline: 2.2791x; 1.2097x over previous
//
#include <hip/hip_runtime.h>
#include <math.h>

#define NNODE 32768
#define NTHR  256
#define NCH   8      // chunks per node: items = 8*n -> ~28K waves, 32 waves/CU
#define MAXF8 224    // per-chunk triangle capacity (F <= 1792)

// fast guarded reciprocal (distance path only; branch boundaries are continuous)
__device__ __forceinline__ float rguard(float d) {
    float dd = (fabsf(d) < 1e-12f) ? 1e-12f : d;
    return __builtin_amdgcn_rcpf(dd);
}

// identical cell computation used by both the marking phase and the sum phase
__device__ __forceinline__ void cell_of(float px, float py, float pz,
                                        int& x0, int& y0, int& z0,
                                        float& wx, float& wy, float& wz) {
#pragma clang fp contract(off)
    float fx = (px + 1.0f) * 0.5f * 31.0f;
    float fy = (py + 1.0f) * 0.5f * 31.0f;
    float fz = (pz + 1.0f) * 0.5f * 31.0f;
    float x0f = floorf(fx), y0f = floorf(fy), z0f = floorf(fz);
    wx = fx - x0f; wy = fy - y0f; wz = fz - z0f;
    x0 = (int)fmaxf(fminf(x0f, 33.0f), -2.0f);
    y0 = (int)fmaxf(fminf(y0f, 33.0f), -2.0f);
    z0 = (int)fmaxf(fminf(z0f, 33.0f), -2.0f);
}

// block-cooperative bbox of hull 1 (any blockDim multiple of 64, <=1024)
__device__ __forceinline__ void bbox_of(const float* __restrict__ verts, int V,
                                        float& ocx, float& ocy, float& ocz,
                                        float& osc) {
#pragma clang fp contract(off)
    const float* v1 = verts + (size_t)V * 3;  // hull 1
    float mn[3] = {1e30f, 1e30f, 1e30f};
    float mx[3] = {-1e30f, -1e30f, -1e30f};
    for (int i = threadIdx.x; i < V; i += blockDim.x) {
        for (int c = 0; c < 3; ++c) {
            float val = v1[i * 3 + c];
            mn[c] = fminf(mn[c], val);
            mx[c] = fmaxf(mx[c], val);
        }
    }
    for (int off = 32; off >= 1; off >>= 1) {
        for (int c = 0; c < 3; ++c) {
            mn[c] = fminf(mn[c], __shfl_down(mn[c], off));
            mx[c] = fmaxf(mx[c], __shfl_down(mx[c], off));
        }
    }
    __shared__ float smn[16][3], smx[16][3];
    int wv = threadIdx.x >> 6, lane = threadIdx.x & 63;
    if (lane == 0)
        for (int c = 0; c < 3; ++c) { smn[wv][c] = mn[c]; smx[wv][c] = mx[c]; }
    __syncthreads();
    const int nw = (int)blockDim.x >> 6;
    float ext = -1e30f, cc[3];
    for (int c = 0; c < 3; ++c) {
        float lo = 1e30f, hi = -1e30f;
        for (int w = 0; w < nw; ++w) {
            lo = fminf(lo, smn[w][c]);
            hi = fmaxf(hi, smx[w][c]);
        }
        cc[c] = (lo + hi) * 0.5f;
        ext = fmaxf(ext, hi - lo);
    }
    ocx = cc[0]; ocy = cc[1]; ocz = cc[2];
    osc = (1.0f + 0.2f) * 0.5f * ext;
    __syncthreads();
}

// per-(node, triangle) update. Distance path uses precomputed dots (continuous
// rewrites only); parity path bit-exact (ab, ac, ap, inv, det as reference).
__device__ __forceinline__ void tri_node(
        float ax, float ay, float az, float abx, float aby, float abz,
        float acx, float acy, float acz, float inv, float det,
        float dbb, float dbc, float dcc,
        float px, float py, float pz, float& mind2, int& h) {
    float apx = px - ax, apy = py - ay, apz = pz - az;
    {
#pragma clang fp contract(fast)
        float d1 = abx * apx + aby * apy + abz * apz;
        float d2 = acx * apx + acy * apy + acz * apz;
        float d3 = d1 - dbb;   // ab.(p-b)
        float d4 = d2 - dbc;   // ac.(p-b)
        float d5 = d1 - dbc;   // ab.(p-c)
        float d6 = d2 - dcc;   // ac.(p-c)
        float vc = d1 * d4 - d3 * d2;
        float vb = d5 * d2 - d1 * d6;
        float va = d3 * d6 - d5 * d4;
        float denom = va + vb + vc;
        float rd = rguard(denom);
        float v_in = vb * rd, w_in = vc * rd;
        float rx = ax + abx * v_in + acx * w_in;
        float ry = ay + aby * v_in + acy * w_in;
        float rz = az + abz * v_in + acz * w_in;
        if (va <= 0.0f && (d4 - d3) >= 0.0f && (d5 - d6) >= 0.0f) {
            float w2 = (d4 - d3) * rguard((d4 - d3) + (d5 - d6));
            rx = ax + abx + (acx - abx) * w2;   // b + (c-b)*w
            ry = ay + aby + (acy - aby) * w2;
            rz = az + abz + (acz - abz) * w2;
        }
        if (vb <= 0.0f && d2 >= 0.0f && d6 <= 0.0f) {
            float w2 = d2 * rguard(d2 - d6);
            rx = ax + acx * w2; ry = ay + acy * w2; rz = az + acz * w2;
        }
        if (vc <= 0.0f && d1 >= 0.0f && d3 <= 0.0f) {
            float w2 = d1 * rguard(d1 - d3);
            rx = ax + abx * w2; ry = ay + aby * w2; rz = az + abz * w2;
        }
        if (d6 >= 0.0f && d5 <= d6) { rx = ax + acx; ry = ay + acy; rz = az + acz; }
        if (d3 >= 0.0f && d4 <= d3) { rx = ax + abx; ry = ay + aby; rz = az + abz; }
        if (d1 <= 0.0f && d2 <= 0.0f) { rx = ax; ry = ay; rz = az; }
        float ddx = px - rx, ddy = py - ry, ddz = pz - rz;
        mind2 = fminf(mind2, ddx * ddx + ddy * ddy + ddz * ddz);
    }
    {
#pragma clang fp contract(off)
        float u = (apy * (-acz) + apz * acy) * inv;
        float qx = apy * abz - apz * aby;
        float qy = apz * abx - apx * abz;
        float qz = apx * aby - apy * abx;
        float v = qx * inv;
        float tt = (acx * qx + acy * qy + acz * qz) * inv;
        h += (fabsf(det) > 1e-9f && u >= 0.0f && u <= 1.0f && v >= 0.0f &&
              (u + v) <= 1.0f && tt > 0.0f) ? 1 : 0;
    }
}

// ---- setup: block0 = LDS-bitmap mark+compact; blocks >=1 = triangle records;
//      ALL blocks grid-stride d2b/hits init (atomics in k_main need it). ----
__global__ void __launch_bounds__(NTHR) k_setup(
        const float* __restrict__ verts, const int* __restrict__ faces,
        float* __restrict__ tri, unsigned int* __restrict__ d2b,
        int* __restrict__ hits, int* __restrict__ cnt, int* __restrict__ list,
        int V, int F) {
    float cx0, cy0, cz0, sc;
    bbox_of(verts, V, cx0, cy0, cz0, sc);
    const int b = (int)blockIdx.x, tid = threadIdx.x;

    // grid-strided init of d2b/hits
    for (int t = b * NTHR + tid; t < NNODE; t += (int)gridDim.x * NTHR) {
        d2b[t] = 0xFFFFFFFFu;
        hits[t] = 0;
    }

    if (b == 0) {
        __shared__ unsigned bm[NNODE / 32];   // 4 KB bitmap
        __shared__ int scnt[NTHR];
        for (int k = 0; k < 4; ++k) bm[tid * 4 + k] = 0u;
        __syncthreads();
        for (int i = tid; i < V; i += NTHR) {
#pragma clang fp contract(off)
            float px = (verts[i * 3 + 0] - cx0) / sc;  // hull-0 vertex
            float py = (verts[i * 3 + 1] - cy0) / sc;
            float pz = (verts[i * 3 + 2] - cz0) / sc;
            int x0, y0, z0; float wx, wy, wz;
            cell_of(px, py, pz, x0, y0, z0, wx, wy, wz);
            for (int k = 0; k < 8; ++k) {
                int zi = z0 + ((k >> 2) & 1), yi = y0 + ((k >> 1) & 1),
                    xi = x0 + (k & 1);
                if ((unsigned)zi < 32u && (unsigned)yi < 32u && (unsigned)xi < 32u) {
                    int node = (zi * 32 + yi) * 32 + xi;
                    atomicOr(&bm[node >> 5], 1u << (node & 31));
                }
            }
        }
        __syncthreads();
        unsigned w0 = bm[tid * 4 + 0], w1 = bm[tid * 4 + 1],
                 w2 = bm[tid * 4 + 2], w3 = bm[tid * 4 + 3];
        int c = __popc(w0) + __popc(w1) + __popc(w2) + __popc(w3);
        scnt[tid] = c;
        __syncthreads();
        for (int off = 1; off < NTHR; off <<= 1) {  // Hillis-Steele inclusive scan
            int v_ = (tid >= off) ? scnt[tid - off] : 0;
            __syncthreads();
            scnt[tid] += v_;
            __syncthreads();
        }
        if (tid == NTHR - 1) cnt[0] = scnt[NTHR - 1];
        int off = scnt[tid] - c;
        unsigned wsv[4] = {w0, w1, w2, w3};
        for (int k = 0; k < 4; ++k) {
            unsigned w = wsv[k];
            int basebit = (tid * 4 + k) * 32;
            while (w) {
                int bb = __ffs(w) - 1;
                list[off++] = basebit + bb;
                w &= w - 1;
            }
        }
    } else {
        // record: a(3) ab(3) ac(3) inv det |ab|^2 ab.ac |ac|^2 pad pad
        int f = (b - 1) * NTHR + tid;
        if (f < F) {
#pragma clang fp contract(off)
            const float* v1 = verts + (size_t)V * 3;
            int i0 = faces[f * 3 + 0], i1 = faces[f * 3 + 1], i2 = faces[f * 3 + 2];
            float ax = (v1[i0 * 3 + 0] - cx0) / sc, ay = (v1[i0 * 3 + 1] - cy0) / sc,
                  az = (v1[i0 * 3 + 2] - cz0) / sc;
            float bx = (v1[i1 * 3 + 0] - cx0) / sc, by = (v1[i1 * 3 + 1] - cy0) / sc,
                  bz = (v1[i1 * 3 + 2] - cz0) / sc;
            float cx = (v1[i2 * 3 + 0] - cx0) / sc, cy = (v1[i2 * 3 + 1] - cy0) / sc,
                  cz = (v1[i2 * 3 + 2] - cz0) / sc;
            float abx = bx - ax, aby = by - ay, abz = bz - az;
            float acx = cx - ax, acy = cy - ay, acz = cz - az;
            float det = aby * (-acz) + abz * acy;
            float dd = (fabsf(det) < 1e-12f) ? 1e-12f : det;
            float inv = 1.0f / dd;  // IEEE — parity test must stay bit-exact
            float* r = tri + (size_t)f * 16;
            r[0] = ax;  r[1] = ay;  r[2] = az;
            r[3] = abx; r[4] = aby; r[5] = abz;
            r[6] = acx; r[7] = acy; r[8] = acz;
            r[9] = inv; r[10] = det;
            r[11] = abx * abx + aby * aby + abz * abz;
            r[12] = abx * acx + aby * acy + abz * acz;
            r[13] = acx * acx + acy * acy + acz * acz;
            r[14] = 0.0f; r[15] = 0.0f;
        }
    }
}

// ---- main: block = (node-group-of-4, 1/8 triangle chunk). Chunk staged once
//      in LDS (12.5 KB -> 8 blocks/CU -> 32 waves/CU); each of the 4 waves
//      computes one node vs the chunk; one atomic pair per (node, chunk). ----
__global__ void __launch_bounds__(NTHR) k_main(
        const float* __restrict__ tri, const int* __restrict__ list,
        const int* __restrict__ cnt, unsigned int* __restrict__ d2b,
        int* __restrict__ hits, int F) {
    const int n = cnt[0];
    const int group = (int)blockIdx.x >> 3;
    if (group * 4 >= n) return;                 // uniform early-exit
    const int c = (int)blockIdx.x & 7;
    const int F8 = (F + NCH - 1) / NCH;
    const int cbase = c * F8;
    const int tn = min(F8, F - cbase);
    if (tn <= 0) return;                        // uniform

    __shared__ float s[14][MAXF8];
    const int tid = threadIdx.x, lane = tid & 63;
    for (int j = tid; j < tn; j += NTHR) {
        const float4* g = (const float4*)(tri + (size_t)(cbase + j) * 16);
        float4 r0 = g[0], r1 = g[1], r2 = g[2], r3 = g[3];
        s[0][j] = r0.x;  s[1][j] = r0.y;  s[2][j] = r0.z;  s[3][j] = r0.w;
        s[4][j] = r1.x;  s[5][j] = r1.y;  s[6][j] = r1.z;  s[7][j] = r1.w;
        s[8][j] = r2.x;  s[9][j] = r2.y;  s[10][j] = r2.z; s[11][j] = r2.w;
        s[12][j] = r3.x; s[13][j] = r3.y;
    }
    __syncthreads();

    const int idx = group * 4 + (tid >> 6);
    const int node = (idx < n) ? list[idx] : -1;
    float px = 0, py = 0, pz = 0;
    if (node >= 0) {
#pragma clang fp contract(off)
        px = (float)((double)(node & 31) * (2.0 / 31.0) - 1.0);
        py = (float)((double)((node >> 5) & 31) * (2.0 / 31.0) - 1.0);
        pz = (float)((double)(node >> 10) * (2.0 / 31.0) - 1.0);
    }
    float m = 1e30f;
    int h = 0;
    if (node >= 0) {
        for (int mi = 0; mi * 64 < tn; ++mi) {
            int j = lane + mi * 64;
            if (j < tn) {
                tri_node(s[0][j], s[1][j], s[2][j], s[3][j], s[4][j], s[5][j],
                         s[6][j], s[7][j], s[8][j], s[9][j], s[10][j],
                         s[11][j], s[12][j], s[13][j], px, py, pz, m, h);
            }
        }
    }
    for (int off = 32; off >= 1; off >>= 1) {
        m = fminf(m, __shfl_xor(m, off));
        h += __shfl_xor(h, off);
    }
    if (lane == 0 && node >= 0) {
        atomicMin(d2b + node, __float_as_uint(m));
        atomicAdd(hits + node, h);
    }
}

// ---- trilinear sample at hull-0 vertices + reduce (one 1024-thread block) ----
__global__ void k_sum(const float* __restrict__ verts,
                      const unsigned int* __restrict__ d2b, const int* __restrict__ hits,
                      float* __restrict__ out, int V) {
    float cx, cy, cz, sc;
    bbox_of(verts, V, cx, cy, cz, sc);
    {
#pragma clang fp contract(off)
        __shared__ float sm[1024];
        const int tid = threadIdx.x;
        float val = 0.0f;
        for (int i = tid; i < V; i += 1024) {
            float px = (verts[i * 3 + 0] - cx) / sc;
            float py = (verts[i * 3 + 1] - cy) / sc;
            float pz = (verts[i * 3 + 2] - cz) / sc;
            int x0, y0, z0; float wx, wy, wz;
            cell_of(px, py, pz, x0, y0, z0, wx, wy, wz);
            auto corner = [&](int zi, int yi, int xi, float w) -> float {
#pragma clang fp contract(off)
                bool valid = (zi >= 0) && (zi <= 31) && (yi >= 0) && (yi <= 31) &&
                             (xi >= 0) && (xi <= 31);
                int zc = min(max(zi, 0), 31);
                int yc = min(max(yi, 0), 31);
                int xc = min(max(xi, 0), 31);
                int idx = (zc * 32 + yc) * 32 + xc;
                float vv = (hits[idx] & 1)
                               ? sqrtf(fmaxf(__uint_as_float(d2b[idx]), 0.0f))
                               : 0.0f;
                return valid ? vv * w : 0.0f;
            };
            val += corner(z0, y0, x0, (1.0f - wz) * (1.0f - wy) * (1.0f - wx))
                 + corner(z0, y0, x0 + 1, (1.0f - wz) * (1.0f - wy) * wx)
                 + corner(z0, y0 + 1, x0, (1.0f - wz) * wy * (1.0f - wx))
                 + corner(z0, y0 + 1, x0 + 1, (1.0f - wz) * wy * wx)
                 + corner(z0 + 1, y0, x0, wz * (1.0f - wy) * (1.0f - wx))
                 + corner(z0 + 1, y0, x0 + 1, wz * (1.0f - wy) * wx)
                 + corner(z0 + 1, y0 + 1, x0, wz * wy * (1.0f - wx))
                 + corner(z0 + 1, y0 + 1, x0 + 1, wz * wy * wx);
        }
        sm[tid] = val;
        __syncthreads();
        for (int ss = 512; ss >= 1; ss >>= 1) {
            if (tid < ss) sm[tid] += sm[tid + ss];
            __syncthreads();
        }
        if (tid == 0) out[0] = sm[0] * 0.25f;  // / H^2, H=2
    }
}

extern "C" void kernel_launch(void* const* d_in, const int* in_sizes, int n_in,
                              void* d_out, int out_size, void* d_ws, size_t ws_size,
                              hipStream_t stream) {
    const float* verts = (const float*)d_in[0];
    const int* faces = (const int*)d_in[1];
    float* out = (float*)d_out;
    float* ws = (float*)d_ws;

    int V = in_sizes[0] / 6;  // 2 hulls x 3 comps
    int F = in_sizes[1] / 3;

    float* tri = ws;                                   // 16*F floats (64B records)
    unsigned int* d2b = (unsigned int*)(tri + 16 * (size_t)F);
    int* hits = (int*)(d2b + NNODE);
    int* cnt = hits + NNODE;
    int* list = cnt + 1;                               // up to 8*V entries

    int nrec = (F + NTHR - 1) / NTHR;
    int nmax = 8 * V; if (nmax > NNODE) nmax = NNODE;  // upper bound on cnt
    int nblk_main = ((nmax + 3) / 4) * NCH;            // (node-group, chunk) blocks

    k_setup<<<1 + nrec, NTHR, 0, stream>>>(verts, faces, tri, d2b, hits, cnt, list,
                                           V, F);
    k_main<<<nblk_main, NTHR, 0, stream>>>(tri, list, cnt, d2b, hits, F);
    k_sum<<<1, 1024, 0, stream>>>(verts, d2b, hits, out, V);
}